// Round 18
// baseline (194.893 us; speedup 1.0000x reference)
//
#include <hip/hip_runtime.h>
#include <hip/hip_bf16.h>

// ---------------------------------------------------------------------------
// ShuffleRowAttention: B=16, N=1024, DIM=768, H=12, DH=64. fp32 in/out
// (runtime-detected). Round 24:
//  * R23 post-mortem: phase-merge null/slightly neg (82.0-82.5 vs 81.0-81.3).
//    attn structural ledger complete: dbuf 81.0/81.2/81.3 | counted 82.2 |
//    merged 82.0 | Ps-68 98.6 -> binder intrinsic to 4-wave barrier-per-kt.
//  * This round: attn reverted to the R22 two-half compute (best measured)
//    + T5 s_setprio(1)/(0) around the QK^T and PV MFMA clusters (softmax at
//    prio 0). Guide m191: +4-7% on attn (waves drift within compute ->
//    role diversity); m190: null on lockstep GEMM. Never tried on attn
//    this session. One effective change vs the 81.0 baseline.
//  * gemm (R19 256x128 triple-buffer), prep (R16 fused) unchanged.
// ---------------------------------------------------------------------------

typedef __bf16 bf16x8 __attribute__((ext_vector_type(8)));
typedef __bf16 bf16x4 __attribute__((ext_vector_type(4)));
typedef float  f32x4  __attribute__((ext_vector_type(4)));

__device__ __forceinline__ f32x4 mfma16(bf16x8 a, bf16x8 b, f32x4 c) {
    return __builtin_amdgcn_mfma_f32_16x16x32_bf16(a, b, c, 0, 0, 0);
}

// async 16B/lane global->LDS: lds base wave-uniform; lane i deposits at +16*i.
__device__ __forceinline__ void async16(const void* g, void* l) {
    __builtin_amdgcn_global_load_lds(
        (const __attribute__((address_space(1))) unsigned int*)g,
        (__attribute__((address_space(3))) unsigned int*)l,
        16, 0, 0);
}

// ---------------------------------------------------------------------------
// Fused prep: dtype-detect (per block, from its own source) + X fp32->bf16
// convert + Wqkv/Wout transpose. Blocks [0,1024): convert X; [1024,1456):
// transpose Wqkv (768x2304); [1456,1600): transpose Wout (768x768).
// ---------------------------------------------------------------------------
__global__ __launch_bounds__(256)
void prep(const void* __restrict__ x, __bf16* __restrict__ Xc,
          const void* __restrict__ Wqkv, __bf16* __restrict__ Wqt,
          const void* __restrict__ Wout, __bf16* __restrict__ Wot,
          int* __restrict__ flag) {
    __shared__ __bf16 tile[64][65];
    __shared__ int cnt;
    const int bid = blockIdx.x;
    const int tid = threadIdx.x;

    const unsigned short* raw =
        (bid < 1024) ? (const unsigned short*)x
                     : (bid < 1456) ? (const unsigned short*)Wqkv
                                    : (const unsigned short*)Wout;
    if (tid == 0) cnt = 0;
    __syncthreads();
    int local = 0;
    for (int i = tid; i < 2048; i += 256) {
        unsigned e = (raw[i] >> 7) & 0xFFu;
        if (e >= 0xC0u) local++;
    }
    atomicAdd(&cnt, local);
    __syncthreads();
    const int f = (cnt > 16) ? 1 : 0;
    if (bid == 0 && tid == 0) *flag = f;

    if (bid < 1024) {
        const int n4 = 16384 * 768 / 4;
        int i = bid * 256 + tid;
        const int stride = 1024 * 256;
        if (f) {
            const float4* s = (const float4*)x;
            for (; i < n4; i += stride) {
                float4 v = s[i];
                bf16x4 o;
                o[0] = (__bf16)v.x; o[1] = (__bf16)v.y;
                o[2] = (__bf16)v.z; o[3] = (__bf16)v.w;
                *(bf16x4*)&Xc[(size_t)i * 4] = o;
            }
        } else {
            const ushort4* s = (const ushort4*)x;
            for (; i < n4; i += stride) *(ushort4*)&Xc[(size_t)i * 4] = s[i];
        }
    } else {
        const void* in;
        __bf16* out;
        int R, C, c0, r0;
        if (bid < 1456) {
            int t = bid - 1024;           // 36 x 12 tiles
            in = Wqkv; out = Wqt; R = 768; C = 2304;
            c0 = (t % 36) * 64; r0 = (t / 36) * 64;
        } else {
            int t = bid - 1456;           // 12 x 12 tiles
            in = Wout; out = Wot; R = 768; C = 768;
            c0 = (t % 12) * 64; r0 = (t / 12) * 64;
        }
        const int tx = tid & 63, ty = tid >> 6;
#pragma unroll
        for (int k = 0; k < 16; ++k) {
            int r = ty + 4 * k;
            size_t idx = (size_t)(r0 + r) * C + c0 + tx;
            tile[r][tx] = f ? (__bf16)((const float*)in)[idx] : ((const __bf16*)in)[idx];
        }
        __syncthreads();
#pragma unroll
        for (int k = 0; k < 16; ++k) {
            int cc = ty + 4 * k;
            out[(size_t)(c0 + cc) * R + r0 + tx] = tile[tx][cc];
        }
    }
}

// ---------------------------------------------------------------------------
// GEMM: C[M x N] = A[M x K] * Bt[N x K]^T (+ bias); bf16 in, fp32 acc.
// R19: 256x128 tile, BK=32, 4 waves (wave tile 128x64), 16x16x32 MFMA.
//  - LDS TRIPLE buffer: buf b at smem + b*24576 { A[256x32] @ +0 (16 KB),
//    B[128x32] @ +16384 (8 KB) }. 16B-chunk slot s of row r holds global
//    chunk s^((r>>1)&3) (XOR swizzle; conflict-free ds_read_b128; staged via
//    pre-swizzled global col). 72 KB total -> 2 blocks/CU.
//  - Tile kt: { s_waitcnt vmcnt(6) lgkmcnt(0); s_barrier; stage(kt+2) ->
//    buf (kt+2)%3 (6 async16/wave); 12x ds_read_b128 + 32 MFMA on buf kt%3 }.
//  - Identity tile mapping, M-fast dispatch.
//  - nkt = K/32 must be 24 (K=768): 7 literal groups of 3 + 3-tile tail.
// MODE 0: C bf16, no bias; V-range blocks (bn>=1536) write transposed to vt.
// MODE 1: C/bias dtype per flag.
// ---------------------------------------------------------------------------
#define GM4(MI, AF)                                                     \
    acc[MI][0] = mfma16(AF, bq0, acc[MI][0]);                           \
    acc[MI][1] = mfma16(AF, bq1, acc[MI][1]);                           \
    acc[MI][2] = mfma16(AF, bq2, acc[MI][2]);                           \
    acc[MI][3] = mfma16(AF, bq3, acc[MI][3])

#define GSTAGE(ST) do {                                                 \
    async16(gA0, smem + (ST) + stA);                                    \
    async16(gA1, smem + (ST) + stA + 1024);                             \
    async16(gA2, smem + (ST) + stA + 2048);                             \
    async16(gA3, smem + (ST) + stA + 3072);                             \
    async16(gB0, smem + (ST) + 16384 + stB);                            \
    async16(gB1, smem + (ST) + 16384 + stB + 1024);                     \
    gA0 += 32; gA1 += 32; gA2 += 32; gA3 += 32;                         \
    gB0 += 32; gB1 += 32;                                               \
} while (0)

// VMK: 6 -> vmcnt(6), 0 -> vmcnt(0). Wait at TOP (prior ds_reads complete +
// this tile's staging landed), barrier, stage, read frags, 32 MFMA.
#define GTILE(RD, ST, DO_STAGE, VMK) do {                               \
    if ((VMK) == 6)                                                     \
        asm volatile("s_waitcnt vmcnt(6) lgkmcnt(0)" ::: "memory");     \
    else                                                                \
        asm volatile("s_waitcnt vmcnt(0) lgkmcnt(0)" ::: "memory");     \
    __builtin_amdgcn_s_barrier();                                       \
    if (DO_STAGE) GSTAGE(ST);                                           \
    bf16x8 af0 = *(const bf16x8*)(smem + (RD) + abase + 0 * 1024);      \
    bf16x8 af1 = *(const bf16x8*)(smem + (RD) + abase + 1 * 1024);      \
    bf16x8 af2 = *(const bf16x8*)(smem + (RD) + abase + 2 * 1024);      \
    bf16x8 af3 = *(const bf16x8*)(smem + (RD) + abase + 3 * 1024);      \
    bf16x8 af4 = *(const bf16x8*)(smem + (RD) + abase + 4 * 1024);      \
    bf16x8 af5 = *(const bf16x8*)(smem + (RD) + abase + 5 * 1024);      \
    bf16x8 af6 = *(const bf16x8*)(smem + (RD) + abase + 6 * 1024);      \
    bf16x8 af7 = *(const bf16x8*)(smem + (RD) + abase + 7 * 1024);      \
    bf16x8 bq0 = *(const bf16x8*)(smem + (RD) + bbase + 0 * 1024);      \
    bf16x8 bq1 = *(const bf16x8*)(smem + (RD) + bbase + 1 * 1024);      \
    bf16x8 bq2 = *(const bf16x8*)(smem + (RD) + bbase + 2 * 1024);      \
    bf16x8 bq3 = *(const bf16x8*)(smem + (RD) + bbase + 3 * 1024);      \
    GM4(0, af0); GM4(1, af1); GM4(2, af2); GM4(3, af3);                 \
    GM4(4, af4); GM4(5, af5); GM4(6, af6); GM4(7, af7);                 \
} while (0)

template <int MODE>
__global__ __launch_bounds__(256, 2)
void gemm_bt(const __bf16* __restrict__ A, int lda,
             const __bf16* __restrict__ Bt,
             const void* __restrict__ bias,
             void* __restrict__ Cout, int ldc,
             int K, const int* __restrict__ flag,
             __bf16* __restrict__ vt) {
    __shared__ __align__(16) char smem[73728];
    const int tid  = threadIdx.x;
    const int wid  = tid >> 6;
    const int lane = tid & 63;
    const int quad = lane >> 4;
    const int l15  = lane & 15;

    // identity tile mapping, M-fast
    const int bm = blockIdx.x * 256;
    const int bn = blockIdx.y * 128;

    const int wm = (wid & 1) * 128;   // M half of 256
    const int wn = (wid >> 1) * 64;   // N half of 128
    const int srow  = lane >> 2;
    const int sslot = lane & 3;

    // staging: pre-swizzled global col chunk (same for all rows: base mult of 16)
    const int cchunk = ((sslot ^ ((srow >> 1) & 3)) << 3);
    // A: wave wid covers rows [wid*64, wid*64+64), 4 async16 (16 rows each)
    const __bf16* gA0 = A + (size_t)(bm + wid * 64 +  0 + srow) * lda + cchunk;
    const __bf16* gA1 = A + (size_t)(bm + wid * 64 + 16 + srow) * lda + cchunk;
    const __bf16* gA2 = A + (size_t)(bm + wid * 64 + 32 + srow) * lda + cchunk;
    const __bf16* gA3 = A + (size_t)(bm + wid * 64 + 48 + srow) * lda + cchunk;
    // B: wave wid covers rows [wid*32, wid*32+32), 2 async16
    const __bf16* gB0 = Bt + (size_t)(bn + wid * 32 +  0 + srow) * K + cchunk;
    const __bf16* gB1 = Bt + (size_t)(bn + wid * 32 + 16 + srow) * K + cchunk;
    const int stA = wid * 4096;   // byte offset of wave's A stage region
    const int stB = wid * 2048;   // byte offset within B region

    // frag read bases (swizzle slot is mi/ni-invariant: (rf>>1)&3 == (l15>>1)&3)
    const int sl = (quad ^ ((l15 >> 1) & 3)) * 16;
    const int abase = (wm + l15) * 64 + sl;            // + mi*1024
    const int bbase = 16384 + (wn + l15) * 64 + sl;    // + ni*1024

    f32x4 acc[8][4];
#pragma unroll
    for (int i = 0; i < 8; ++i)
#pragma unroll
        for (int j = 0; j < 4; ++j) acc[i][j] = (f32x4)0.0f;

    // ---- prologue: stage tile 0 -> buf0, tile 1 -> buf1 (12 loads in flight)
    GSTAGE(0);
    GSTAGE(24576);

    // ---- main loop: 24 tiles = 7 literal groups of 3 + 3-tile tail ----
#pragma unroll 1
    for (int g = 0; g < 7; ++g) {
        GTILE(0,     49152, true, 6);   // tile 3g+0: read buf0, stage -> buf2
        GTILE(24576, 0,     true, 6);   // tile 3g+1: read buf1, stage -> buf0
        GTILE(49152, 24576, true, 6);   // tile 3g+2: read buf2, stage -> buf1
    }
    GTILE(0,     49152, true,  6);      // tile 21: stages tile 23 -> buf2
    GTILE(24576, 0,     false, 6);      // tile 22
    GTILE(49152, 0,     false, 0);      // tile 23: final drain

    // ---- MODE 0 V-range blocks: write acc transposed to Vt, skip Cout ----
    if (MODE == 0 && bn >= 1536) {
        const int bq = bm >> 10;                         // batch index
        const int n0 = (bm & 1023) + wm + quad * 4;      // n base for this lane
        const int colb = bn - 1536 + wn;                 // V feature base
        // vt row = b*768 + col
#pragma unroll
        for (int mi = 0; mi < 8; ++mi)
#pragma unroll
            for (int ni = 0; ni < 4; ++ni) {
                int col = colb + ni * 16 + l15;
                bf16x4 v;
                v[0] = (__bf16)acc[mi][ni][0];
                v[1] = (__bf16)acc[mi][ni][1];
                v[2] = (__bf16)acc[mi][ni][2];
                v[3] = (__bf16)acc[mi][ni][3];
                *(bf16x4*)&vt[((size_t)bq * 768 + col) * 1024 + n0 + mi * 16] = v;
            }
        return;   // block-uniform branch
    }

    // ---- epilogue: bias add in-register, then LDS-staged coalesced stores ----
    const int f = (MODE == 1) ? *flag : 0;
    if (MODE == 1) {
#pragma unroll
        for (int ni = 0; ni < 4; ++ni) {
            int col = bn + wn + ni * 16 + l15;
            float bv = f ? ((const float*)bias)[col] : (float)((const __bf16*)bias)[col];
#pragma unroll
            for (int mi = 0; mi < 8; ++mi)
#pragma unroll
                for (int rg = 0; rg < 4; ++rg) acc[mi][ni][rg] += bv;
        }
    }

    if (MODE == 0 || !f) {
        // bf16 output: 8 chunks of 32 rows; cs = [32][136] bf16 (8704 B)
        __bf16* cs = (__bf16*)smem;
#pragma unroll
        for (int c = 0; c < 8; ++c) {
            __syncthreads();
            if (wm == (c >> 2) * 128) {
#pragma unroll
                for (int mloc = 0; mloc < 2; ++mloc) {
#pragma unroll
                    for (int ni = 0; ni < 4; ++ni) {
                        int col = wn + ni * 16 + l15;
#pragma unroll
                        for (int rg = 0; rg < 4; ++rg)
                            cs[(mloc * 16 + quad * 4 + rg) * 136 + col] =
                                (__bf16)acc[(c & 3) * 2 + mloc][ni][rg];
                    }
                }
            }
            __syncthreads();
#pragma unroll
            for (int p = 0; p < 2; ++p) {
                int row  = p * 16 + (tid >> 4);
                int colc = tid & 15;
                bf16x8 v = *(const bf16x8*)&cs[row * 136 + colc * 8];
                *(bf16x8*)((__bf16*)Cout + (size_t)(bm + c * 32 + row) * ldc + bn + colc * 8) = v;
            }
        }
    } else {
        // fp32 output: 16 chunks of 16 rows; cs = [16][132] float (8448 B)
        float* cs = (float*)smem;
#pragma unroll
        for (int c = 0; c < 16; ++c) {
            __syncthreads();
            if (wm == (c >> 3) * 128) {
#pragma unroll
                for (int ni = 0; ni < 4; ++ni) {
                    int col = wn + ni * 16 + l15;
#pragma unroll
                    for (int rg = 0; rg < 4; ++rg)
                        cs[(quad * 4 + rg) * 132 + col] = acc[c & 7][ni][rg];
                }
            }
            __syncthreads();
#pragma unroll
            for (int p = 0; p < 2; ++p) {
                int row  = p * 8 + (tid >> 5);
                int colc = tid & 31;
                float4 v = *(const float4*)&cs[row * 132 + colc * 4];
                *(float4*)((float*)Cout + (size_t)(bm + c * 16 + row) * ldc + bn + colc * 4) = v;
            }
        }
    }
}

// ---------------------------------------------------------------------------
// Flash attention, S^T formulation, async16 staging. Grid (B*H, N/128) --
// bh is blockIdx.x so id%8 = bh%8: all q-tiles of a head pin to one XCD.
// R22 configuration (best measured: 81.0 us) + R24 T5 setprio around the
// QK^T and PV MFMA clusters (waves drift within compute -> role diversity;
// m191 measured +4-7% on attn).
// LDS: K buf k @ k*8192; V buf k @ 16384 + k*8192; Ps @ 32768 (55296 total).
// ---------------------------------------------------------------------------
__global__ __launch_bounds__(256, 2)
void attn(const __bf16* qkv, const __bf16* __restrict__ vt,
          const int* __restrict__ perm, __bf16* O, int ldo) {
    __shared__ __align__(16) char smem[55296];
    __bf16* Qs = (__bf16*)smem;              // 128 x 64 (dies after qf loaded)
    __bf16* Ps = (__bf16*)(smem + 32768);    // 4 waves x [32 x 88]

    const int tid  = threadIdx.x;
    const int wid  = tid >> 6;
    const int lane = tid & 63;
    const int quad = lane >> 4;
    const int l15  = lane & 15;
    const int bh = blockIdx.x;
    const int q0 = blockIdx.y * 128;
    const int b = bh / 12, h = bh % 12;
    const size_t row_base = (size_t)b * 1024;
    const int qcol = h * 64;
    const int kcol = 768 + h * 64;
    const int srow8  = lane >> 3;
    const int sslot8 = lane & 7;
    __bf16* Pw = Ps + wid * (32 * 88);

    // ---- stage Q (perm-gathered rows) ----
#pragma unroll
    for (int is = 0; is < 4; ++is) {
        int r = is * 32 + wid * 8 + srow8;
        int gr = perm[q0 + r];
        int chunk = sslot8 ^ (r & 7);
        async16(qkv + (row_base + gr) * 2304 + qcol + chunk * 8,
                &Qs[(is * 32 + wid * 8) * 64]);
    }
    __syncthreads();

    bf16x8 qf[2][2];
#pragma unroll
    for (int mi = 0; mi < 2; ++mi) {
        int r = wid * 32 + mi * 16 + l15;
#pragma unroll
        for (int ks = 0; ks < 2; ++ks)
            qf[mi][ks] = *(const bf16x8*)&Qs[r * 64 + (((ks * 4 + quad) ^ (r & 7)) * 8)];
    }
    // my qf reads must complete before staging overwrites the Qs region
    asm volatile("s_waitcnt lgkmcnt(0)" ::: "memory");
    __builtin_amdgcn_sched_barrier(0);
    __builtin_amdgcn_s_barrier();

    // ---- loop-invariant LDS element offsets ----
    const int off0 = l15 * 64 + (((0 * 4 + quad) ^ (l15 & 7)) * 8); // ks/ks2 = 0
    const int off1 = l15 * 64 + (((1 * 4 + quad) ^ (l15 & 7)) * 8); // ks/ks2 = 1
    const int pwb  = l15 * 88 + quad * 4;   // + mi*1408 + ki*16 (immediates)
    const int pfb  = l15 * 88 + quad * 8;   // + mi*1408 + ks2*32 (immediates)

    // ---- held global staging pointers (incremented per stage) ----
    const int rK = wid * 8 + srow8;                 // +32 for second chunk
    const int ck = sslot8 ^ (rK & 7);               // (is*32)&7 == 0
    const __bf16* kg0 = qkv + (row_base + rK) * 2304 + kcol + ck * 8;
    const __bf16* kg1 = kg0 + (size_t)32 * 2304;
    const __bf16* vg0 = vt + ((size_t)bh * 64 + rK) * 1024 + ck * 8;
    const __bf16* vg1 = vg0 + (size_t)32 * 1024;

    f32x4 acco[2][4];
#pragma unroll
    for (int mi = 0; mi < 2; ++mi)
#pragma unroll
        for (int ni = 0; ni < 4; ++ni) acco[mi][ni] = (f32x4)0.0f;
    float lsum[2] = {0.0f, 0.0f};

    const float cfac = 0.125f * 1.44269504088896340736f;

    // stage into buf kb: K @ kb*8192, V @ 16384 + kb*8192
#define ASTAGE(KB, VB) do {                                             \
        async16(kg0, smem + (KB) + wid * 1024);                         \
        async16(kg1, smem + (KB) + 4096 + wid * 1024);                  \
        async16(vg0, smem + (VB) + wid * 1024);                         \
        async16(vg1, smem + (VB) + 4096 + wid * 1024);                  \
        kg0 += (size_t)64 * 2304; kg1 += (size_t)64 * 2304;             \
        vg0 += 64; vg1 += 64;                                           \
    } while (0)

    auto compute = [&](const __bf16* Kb, const __bf16* Vb) {
#pragma unroll
        for (int half = 0; half < 2; ++half) {
            // ---- QK^T for ki = half*2 .. half*2+1 ----
            f32x4 accs[2][2];
#pragma unroll
            for (int ki = 0; ki < 2; ++ki)
#pragma unroll
                for (int mi = 0; mi < 2; ++mi) accs[ki][mi] = (f32x4)0.0f;
            __builtin_amdgcn_s_setprio(1);
#pragma unroll
            for (int ks = 0; ks < 2; ++ks) {
                const int off = ks ? off1 : off0;
                bf16x8 kf0 = *(const bf16x8*)&Kb[(half * 2 + 0) * 1024 + off];
                bf16x8 kf1 = *(const bf16x8*)&Kb[(half * 2 + 1) * 1024 + off];
                accs[0][0] = mfma16(kf0, qf[0][ks], accs[0][0]);
                accs[0][1] = mfma16(kf0, qf[1][ks], accs[0][1]);
                accs[1][0] = mfma16(kf1, qf[0][ks], accs[1][0]);
                accs[1][1] = mfma16(kf1, qf[1][ks], accs[1][1]);
            }
            __builtin_amdgcn_s_setprio(0);

            // ---- softmax (static bias -8; cancels in normalization) ----
#pragma unroll
            for (int ki = 0; ki < 2; ++ki)
#pragma unroll
                for (int mi = 0; mi < 2; ++mi) {
                    bf16x4 pk;
                    float s0 = __builtin_amdgcn_exp2f(accs[ki][mi][0] * cfac - 8.0f);
                    float s1 = __builtin_amdgcn_exp2f(accs[ki][mi][1] * cfac - 8.0f);
                    float s2 = __builtin_amdgcn_exp2f(accs[ki][mi][2] * cfac - 8.0f);
                    float s3 = __builtin_amdgcn_exp2f(accs[ki][mi][3] * cfac - 8.0f);
                    pk[0] = (__bf16)s0; pk[1] = (__bf16)s1;
                    pk[2] = (__bf16)s2; pk[3] = (__bf16)s3;
                    lsum[mi] += (s0 + s1) + (s2 + s3);
                    *(bf16x4*)&Pw[pwb + mi * 1408 + (half * 2 + ki) * 16] = pk;
                }

            // ---- PV for ks2 = half (same-wave LDS RAW; lgkmcnt orders it) ----
            {
                bf16x8 pf0 = *(const bf16x8*)&Pw[pfb + 0 * 1408 + half * 32];
                bf16x8 pf1 = *(const bf16x8*)&Pw[pfb + 1 * 1408 + half * 32];
                const int offv = half ? off1 : off0;
                __builtin_amdgcn_s_setprio(1);
#pragma unroll
                for (int ni = 0; ni < 4; ++ni) {
                    bf16x8 vf = *(const bf16x8*)&Vb[ni * 1024 + offv];
                    acco[0][ni] = mfma16(pf0, vf, acco[0][ni]);
                    acco[1][ni] = mfma16(pf1, vf, acco[1][ni]);
                }
                __builtin_amdgcn_s_setprio(0);
            }
        }
    };

    // ---- prologue: stage kt=0 into buf0 ----
    ASTAGE(0, 16384);

    // ---- main loop: 16 kt, unrolled x2 for literal buffer offsets ----
#pragma unroll 1
    for (int kt2 = 0; kt2 < 8; ++kt2) {
        asm volatile("s_waitcnt vmcnt(0) lgkmcnt(0)" ::: "memory");
        __builtin_amdgcn_s_barrier();
        ASTAGE(8192, 16384 + 8192);
        compute((const __bf16*)smem, (const __bf16*)(smem + 16384));
        asm volatile("s_waitcnt vmcnt(0) lgkmcnt(0)" ::: "memory");
        __builtin_amdgcn_s_barrier();
        if (kt2 < 7) ASTAGE(0, 16384);
        compute((const __bf16*)(smem + 8192), (const __bf16*)(smem + 16384 + 8192));
    }
#undef ASTAGE

#pragma unroll
    for (int off = 16; off < 64; off <<= 1) {
        lsum[0] += __shfl_xor(lsum[0], off, 64);
        lsum[1] += __shfl_xor(lsum[1], off, 64);
    }

#pragma unroll
    for (int mi = 0; mi < 2; ++mi) {
#pragma unroll
        for (int rg = 0; rg < 4; ++rg) {
            float inv = 1.0f / __shfl(lsum[mi], quad * 4 + rg, 64);
            int orow = q0 + wid * 32 + mi * 16 + quad * 4 + rg;
#pragma unroll
            for (int ni = 0; ni < 4; ++ni) {
                int ocol = h * 64 + ni * 16 + l15;
                O[(row_base + orow) * (size_t)ldo + ocol] = (__bf16)(acco[mi][ni][rg] * inv);
            }
        }
    }
}

// ---------------------------------------------------------------------------
// Workspace layout (bytes), total ~130.5 MB (see round-3 comment).
// ---------------------------------------------------------------------------
extern "C" void kernel_launch(void* const* d_in, const int* in_sizes, int n_in,
                              void* d_out, int out_size, void* d_ws, size_t ws_size,
                              hipStream_t stream) {
    (void)in_sizes; (void)n_in; (void)out_size; (void)ws_size;
    const void* x_raw    = d_in[0];
    const void* Wqkv_raw = d_in[1];
    const void* Wout_raw = d_in[2];
    const void* bout_raw = d_in[3];
    const int*  perm     = (const int*)d_in[4];

    char* ws = (char*)d_ws;
    int*    flag = (int*)ws;
    __bf16* Xc   = (__bf16*)(ws + 256);
    __bf16* QKV  = (__bf16*)(ws + 25166080);
    __bf16* Vt   = (__bf16*)(ws + 100663552);
    __bf16* Wqt  = (__bf16*)(ws + 125829376);
    __bf16* Wot  = (__bf16*)(ws + 129368320);
    __bf16* Obuf = QKV + 1536; // O[n][768] in QKV's V columns, ld 2304

    prep<<<1600, 256, 0, stream>>>(x_raw, Xc, Wqkv_raw, Wqt, Wout_raw, Wot, flag);
    gemm_bt<0><<<dim3(64, 18), 256, 0, stream>>>(Xc, 768, Wqt, nullptr, QKV, 2304, 768, nullptr, Vt);
    attn<<<dim3(192, 8), 256, 0, stream>>>(QKV, Vt, perm, Obuf, 2304);
    gemm_bt<1><<<dim3(64, 6), 256, 0, stream>>>(Obuf, 2304, Wot, bout_raw, d_out, 768, 768, flag, nullptr);
}

// Round 19
// 193.069 us; speedup vs baseline: 1.0094x; 1.0094x over previous
//
#include <hip/hip_runtime.h>
#include <hip/hip_bf16.h>

// ---------------------------------------------------------------------------
// ShuffleRowAttention: B=16, N=1024, DIM=768, H=12, DH=64. fp32 in/out
// (runtime-detected). Round 25 (FINAL CONFIG):
//  * R24 post-mortem: T5 setprio on attn HURT (81.0 -> 84.0; m191's +4-7%
//    didn't transfer -- our 4 waves re-converge at a barrier every kt, so
//    priority extends the leading wave's lead into the barrier wait; the
//    m190 lockstep regime, not m191's independent-block regime). Reverted.
//  * attn ledger complete (6 configs): dbuf 81.0/81.2/81.3 | merged 82.0 |
//    counted-triple 82.2 | setprio 84.0 | Ps-68+(256,3) 98.6. GEMM closed
//    at 256x128 counted-triple (R19; 6 variants). Prep fused (R16).
//  * This is the exact R22 best-measured configuration (193.3/193.8 us):
//    fused prep + 256x128 triple-buffer counted-vmcnt GEMM (Vt fused into
//    gemm<0>) + dbuf attn with vmcnt(0)+lgkmcnt(0) WAR fence.
//  * Session: 251 -> ~193.5 us (-23%).
// ---------------------------------------------------------------------------

typedef __bf16 bf16x8 __attribute__((ext_vector_type(8)));
typedef __bf16 bf16x4 __attribute__((ext_vector_type(4)));
typedef float  f32x4  __attribute__((ext_vector_type(4)));

__device__ __forceinline__ f32x4 mfma16(bf16x8 a, bf16x8 b, f32x4 c) {
    return __builtin_amdgcn_mfma_f32_16x16x32_bf16(a, b, c, 0, 0, 0);
}

// async 16B/lane global->LDS: lds base wave-uniform; lane i deposits at +16*i.
__device__ __forceinline__ void async16(const void* g, void* l) {
    __builtin_amdgcn_global_load_lds(
        (const __attribute__((address_space(1))) unsigned int*)g,
        (__attribute__((address_space(3))) unsigned int*)l,
        16, 0, 0);
}

// ---------------------------------------------------------------------------
// Fused prep: dtype-detect (per block, from its own source) + X fp32->bf16
// convert + Wqkv/Wout transpose. Blocks [0,1024): convert X; [1024,1456):
// transpose Wqkv (768x2304); [1456,1600): transpose Wout (768x768).
// ---------------------------------------------------------------------------
__global__ __launch_bounds__(256)
void prep(const void* __restrict__ x, __bf16* __restrict__ Xc,
          const void* __restrict__ Wqkv, __bf16* __restrict__ Wqt,
          const void* __restrict__ Wout, __bf16* __restrict__ Wot,
          int* __restrict__ flag) {
    __shared__ __bf16 tile[64][65];
    __shared__ int cnt;
    const int bid = blockIdx.x;
    const int tid = threadIdx.x;

    const unsigned short* raw =
        (bid < 1024) ? (const unsigned short*)x
                     : (bid < 1456) ? (const unsigned short*)Wqkv
                                    : (const unsigned short*)Wout;
    if (tid == 0) cnt = 0;
    __syncthreads();
    int local = 0;
    for (int i = tid; i < 2048; i += 256) {
        unsigned e = (raw[i] >> 7) & 0xFFu;
        if (e >= 0xC0u) local++;
    }
    atomicAdd(&cnt, local);
    __syncthreads();
    const int f = (cnt > 16) ? 1 : 0;
    if (bid == 0 && tid == 0) *flag = f;

    if (bid < 1024) {
        const int n4 = 16384 * 768 / 4;
        int i = bid * 256 + tid;
        const int stride = 1024 * 256;
        if (f) {
            const float4* s = (const float4*)x;
            for (; i < n4; i += stride) {
                float4 v = s[i];
                bf16x4 o;
                o[0] = (__bf16)v.x; o[1] = (__bf16)v.y;
                o[2] = (__bf16)v.z; o[3] = (__bf16)v.w;
                *(bf16x4*)&Xc[(size_t)i * 4] = o;
            }
        } else {
            const ushort4* s = (const ushort4*)x;
            for (; i < n4; i += stride) *(ushort4*)&Xc[(size_t)i * 4] = s[i];
        }
    } else {
        const void* in;
        __bf16* out;
        int R, C, c0, r0;
        if (bid < 1456) {
            int t = bid - 1024;           // 36 x 12 tiles
            in = Wqkv; out = Wqt; R = 768; C = 2304;
            c0 = (t % 36) * 64; r0 = (t / 36) * 64;
        } else {
            int t = bid - 1456;           // 12 x 12 tiles
            in = Wout; out = Wot; R = 768; C = 768;
            c0 = (t % 12) * 64; r0 = (t / 12) * 64;
        }
        const int tx = tid & 63, ty = tid >> 6;
#pragma unroll
        for (int k = 0; k < 16; ++k) {
            int r = ty + 4 * k;
            size_t idx = (size_t)(r0 + r) * C + c0 + tx;
            tile[r][tx] = f ? (__bf16)((const float*)in)[idx] : ((const __bf16*)in)[idx];
        }
        __syncthreads();
#pragma unroll
        for (int k = 0; k < 16; ++k) {
            int cc = ty + 4 * k;
            out[(size_t)(c0 + cc) * R + r0 + tx] = tile[tx][cc];
        }
    }
}

// ---------------------------------------------------------------------------
// GEMM: C[M x N] = A[M x K] * Bt[N x K]^T (+ bias); bf16 in, fp32 acc.
// R19: 256x128 tile, BK=32, 4 waves (wave tile 128x64), 16x16x32 MFMA.
//  - LDS TRIPLE buffer: buf b at smem + b*24576 { A[256x32] @ +0 (16 KB),
//    B[128x32] @ +16384 (8 KB) }. 16B-chunk slot s of row r holds global
//    chunk s^((r>>1)&3) (XOR swizzle; conflict-free ds_read_b128; staged via
//    pre-swizzled global col). 72 KB total -> 2 blocks/CU.
//  - Tile kt: { s_waitcnt vmcnt(6) lgkmcnt(0); s_barrier; stage(kt+2) ->
//    buf (kt+2)%3 (6 async16/wave); 12x ds_read_b128 + 32 MFMA on buf kt%3 }.
//  - Identity tile mapping, M-fast dispatch.
//  - nkt = K/32 must be 24 (K=768): 7 literal groups of 3 + 3-tile tail.
// MODE 0: C bf16, no bias; V-range blocks (bn>=1536) write transposed to vt.
// MODE 1: C/bias dtype per flag.
// ---------------------------------------------------------------------------
#define GM4(MI, AF)                                                     \
    acc[MI][0] = mfma16(AF, bq0, acc[MI][0]);                           \
    acc[MI][1] = mfma16(AF, bq1, acc[MI][1]);                           \
    acc[MI][2] = mfma16(AF, bq2, acc[MI][2]);                           \
    acc[MI][3] = mfma16(AF, bq3, acc[MI][3])

#define GSTAGE(ST) do {                                                 \
    async16(gA0, smem + (ST) + stA);                                    \
    async16(gA1, smem + (ST) + stA + 1024);                             \
    async16(gA2, smem + (ST) + stA + 2048);                             \
    async16(gA3, smem + (ST) + stA + 3072);                             \
    async16(gB0, smem + (ST) + 16384 + stB);                            \
    async16(gB1, smem + (ST) + 16384 + stB + 1024);                     \
    gA0 += 32; gA1 += 32; gA2 += 32; gA3 += 32;                         \
    gB0 += 32; gB1 += 32;                                               \
} while (0)

// VMK: 6 -> vmcnt(6), 0 -> vmcnt(0). Wait at TOP (prior ds_reads complete +
// this tile's staging landed), barrier, stage, read frags, 32 MFMA.
#define GTILE(RD, ST, DO_STAGE, VMK) do {                               \
    if ((VMK) == 6)                                                     \
        asm volatile("s_waitcnt vmcnt(6) lgkmcnt(0)" ::: "memory");     \
    else                                                                \
        asm volatile("s_waitcnt vmcnt(0) lgkmcnt(0)" ::: "memory");     \
    __builtin_amdgcn_s_barrier();                                       \
    if (DO_STAGE) GSTAGE(ST);                                           \
    bf16x8 af0 = *(const bf16x8*)(smem + (RD) + abase + 0 * 1024);      \
    bf16x8 af1 = *(const bf16x8*)(smem + (RD) + abase + 1 * 1024);      \
    bf16x8 af2 = *(const bf16x8*)(smem + (RD) + abase + 2 * 1024);      \
    bf16x8 af3 = *(const bf16x8*)(smem + (RD) + abase + 3 * 1024);      \
    bf16x8 af4 = *(const bf16x8*)(smem + (RD) + abase + 4 * 1024);      \
    bf16x8 af5 = *(const bf16x8*)(smem + (RD) + abase + 5 * 1024);      \
    bf16x8 af6 = *(const bf16x8*)(smem + (RD) + abase + 6 * 1024);      \
    bf16x8 af7 = *(const bf16x8*)(smem + (RD) + abase + 7 * 1024);      \
    bf16x8 bq0 = *(const bf16x8*)(smem + (RD) + bbase + 0 * 1024);      \
    bf16x8 bq1 = *(const bf16x8*)(smem + (RD) + bbase + 1 * 1024);      \
    bf16x8 bq2 = *(const bf16x8*)(smem + (RD) + bbase + 2 * 1024);      \
    bf16x8 bq3 = *(const bf16x8*)(smem + (RD) + bbase + 3 * 1024);      \
    GM4(0, af0); GM4(1, af1); GM4(2, af2); GM4(3, af3);                 \
    GM4(4, af4); GM4(5, af5); GM4(6, af6); GM4(7, af7);                 \
} while (0)

template <int MODE>
__global__ __launch_bounds__(256, 2)
void gemm_bt(const __bf16* __restrict__ A, int lda,
             const __bf16* __restrict__ Bt,
             const void* __restrict__ bias,
             void* __restrict__ Cout, int ldc,
             int K, const int* __restrict__ flag,
             __bf16* __restrict__ vt) {
    __shared__ __align__(16) char smem[73728];
    const int tid  = threadIdx.x;
    const int wid  = tid >> 6;
    const int lane = tid & 63;
    const int quad = lane >> 4;
    const int l15  = lane & 15;

    // identity tile mapping, M-fast
    const int bm = blockIdx.x * 256;
    const int bn = blockIdx.y * 128;

    const int wm = (wid & 1) * 128;   // M half of 256
    const int wn = (wid >> 1) * 64;   // N half of 128
    const int srow  = lane >> 2;
    const int sslot = lane & 3;

    // staging: pre-swizzled global col chunk (same for all rows: base mult of 16)
    const int cchunk = ((sslot ^ ((srow >> 1) & 3)) << 3);
    // A: wave wid covers rows [wid*64, wid*64+64), 4 async16 (16 rows each)
    const __bf16* gA0 = A + (size_t)(bm + wid * 64 +  0 + srow) * lda + cchunk;
    const __bf16* gA1 = A + (size_t)(bm + wid * 64 + 16 + srow) * lda + cchunk;
    const __bf16* gA2 = A + (size_t)(bm + wid * 64 + 32 + srow) * lda + cchunk;
    const __bf16* gA3 = A + (size_t)(bm + wid * 64 + 48 + srow) * lda + cchunk;
    // B: wave wid covers rows [wid*32, wid*32+32), 2 async16
    const __bf16* gB0 = Bt + (size_t)(bn + wid * 32 +  0 + srow) * K + cchunk;
    const __bf16* gB1 = Bt + (size_t)(bn + wid * 32 + 16 + srow) * K + cchunk;
    const int stA = wid * 4096;   // byte offset of wave's A stage region
    const int stB = wid * 2048;   // byte offset within B region

    // frag read bases (swizzle slot is mi/ni-invariant: (rf>>1)&3 == (l15>>1)&3)
    const int sl = (quad ^ ((l15 >> 1) & 3)) * 16;
    const int abase = (wm + l15) * 64 + sl;            // + mi*1024
    const int bbase = 16384 + (wn + l15) * 64 + sl;    // + ni*1024

    f32x4 acc[8][4];
#pragma unroll
    for (int i = 0; i < 8; ++i)
#pragma unroll
        for (int j = 0; j < 4; ++j) acc[i][j] = (f32x4)0.0f;

    // ---- prologue: stage tile 0 -> buf0, tile 1 -> buf1 (12 loads in flight)
    GSTAGE(0);
    GSTAGE(24576);

    // ---- main loop: 24 tiles = 7 literal groups of 3 + 3-tile tail ----
#pragma unroll 1
    for (int g = 0; g < 7; ++g) {
        GTILE(0,     49152, true, 6);   // tile 3g+0: read buf0, stage -> buf2
        GTILE(24576, 0,     true, 6);   // tile 3g+1: read buf1, stage -> buf0
        GTILE(49152, 24576, true, 6);   // tile 3g+2: read buf2, stage -> buf1
    }
    GTILE(0,     49152, true,  6);      // tile 21: stages tile 23 -> buf2
    GTILE(24576, 0,     false, 6);      // tile 22
    GTILE(49152, 0,     false, 0);      // tile 23: final drain

    // ---- MODE 0 V-range blocks: write acc transposed to Vt, skip Cout ----
    if (MODE == 0 && bn >= 1536) {
        const int bq = bm >> 10;                         // batch index
        const int n0 = (bm & 1023) + wm + quad * 4;      // n base for this lane
        const int colb = bn - 1536 + wn;                 // V feature base
        // vt row = b*768 + col
#pragma unroll
        for (int mi = 0; mi < 8; ++mi)
#pragma unroll
            for (int ni = 0; ni < 4; ++ni) {
                int col = colb + ni * 16 + l15;
                bf16x4 v;
                v[0] = (__bf16)acc[mi][ni][0];
                v[1] = (__bf16)acc[mi][ni][1];
                v[2] = (__bf16)acc[mi][ni][2];
                v[3] = (__bf16)acc[mi][ni][3];
                *(bf16x4*)&vt[((size_t)bq * 768 + col) * 1024 + n0 + mi * 16] = v;
            }
        return;   // block-uniform branch
    }

    // ---- epilogue: bias add in-register, then LDS-staged coalesced stores ----
    const int f = (MODE == 1) ? *flag : 0;
    if (MODE == 1) {
#pragma unroll
        for (int ni = 0; ni < 4; ++ni) {
            int col = bn + wn + ni * 16 + l15;
            float bv = f ? ((const float*)bias)[col] : (float)((const __bf16*)bias)[col];
#pragma unroll
            for (int mi = 0; mi < 8; ++mi)
#pragma unroll
                for (int rg = 0; rg < 4; ++rg) acc[mi][ni][rg] += bv;
        }
    }

    if (MODE == 0 || !f) {
        // bf16 output: 8 chunks of 32 rows; cs = [32][136] bf16 (8704 B)
        __bf16* cs = (__bf16*)smem;
#pragma unroll
        for (int c = 0; c < 8; ++c) {
            __syncthreads();
            if (wm == (c >> 2) * 128) {
#pragma unroll
                for (int mloc = 0; mloc < 2; ++mloc) {
#pragma unroll
                    for (int ni = 0; ni < 4; ++ni) {
                        int col = wn + ni * 16 + l15;
#pragma unroll
                        for (int rg = 0; rg < 4; ++rg)
                            cs[(mloc * 16 + quad * 4 + rg) * 136 + col] =
                                (__bf16)acc[(c & 3) * 2 + mloc][ni][rg];
                    }
                }
            }
            __syncthreads();
#pragma unroll
            for (int p = 0; p < 2; ++p) {
                int row  = p * 16 + (tid >> 4);
                int colc = tid & 15;
                bf16x8 v = *(const bf16x8*)&cs[row * 136 + colc * 8];
                *(bf16x8*)((__bf16*)Cout + (size_t)(bm + c * 32 + row) * ldc + bn + colc * 8) = v;
            }
        }
    } else {
        // fp32 output: 16 chunks of 16 rows; cs = [16][132] float (8448 B)
        float* cs = (float*)smem;
#pragma unroll
        for (int c = 0; c < 16; ++c) {
            __syncthreads();
            if (wm == (c >> 3) * 128) {
#pragma unroll
                for (int ni = 0; ni < 4; ++ni) {
                    int col = wn + ni * 16 + l15;
#pragma unroll
                    for (int rg = 0; rg < 4; ++rg)
                        cs[(quad * 4 + rg) * 132 + col] = acc[c & 7][ni][rg];
                }
            }
            __syncthreads();
#pragma unroll
            for (int p = 0; p < 2; ++p) {
                int row  = p * 8 + (tid >> 5);
                int colc = tid & 31;
                float4 v = *(const float4*)&cs[row * 132 + colc * 4];
                *(float4*)((float*)Cout + (size_t)(bm + c * 16 + row) * ldc + bn + colc * 4) = v;
            }
        }
    }
}

// ---------------------------------------------------------------------------
// Flash attention, S^T formulation, async16 staging. Grid (B*H, N/128) --
// bh is blockIdx.x so id%8 = bh%8: all q-tiles of a head pin to one XCD.
// R22 configuration (best measured: attn 81.0 us): K/V double-buffered;
// per-kt wait vmcnt(0)+lgkmcnt(0) (WAR fence) + s_barrier; stage(kt+1)
// issued right after the barrier so the wait is covered by compute(kt-1).
// LDS: K buf k @ k*8192; V buf k @ 16384 + k*8192; Ps @ 32768 (55296 total).
// ---------------------------------------------------------------------------
__global__ __launch_bounds__(256, 2)
void attn(const __bf16* qkv, const __bf16* __restrict__ vt,
          const int* __restrict__ perm, __bf16* O, int ldo) {
    __shared__ __align__(16) char smem[55296];
    __bf16* Qs = (__bf16*)smem;              // 128 x 64 (dies after qf loaded)
    __bf16* Ps = (__bf16*)(smem + 32768);    // 4 waves x [32 x 88]

    const int tid  = threadIdx.x;
    const int wid  = tid >> 6;
    const int lane = tid & 63;
    const int quad = lane >> 4;
    const int l15  = lane & 15;
    const int bh = blockIdx.x;
    const int q0 = blockIdx.y * 128;
    const int b = bh / 12, h = bh % 12;
    const size_t row_base = (size_t)b * 1024;
    const int qcol = h * 64;
    const int kcol = 768 + h * 64;
    const int srow8  = lane >> 3;
    const int sslot8 = lane & 7;
    __bf16* Pw = Ps + wid * (32 * 88);

    // ---- stage Q (perm-gathered rows) ----
#pragma unroll
    for (int is = 0; is < 4; ++is) {
        int r = is * 32 + wid * 8 + srow8;
        int gr = perm[q0 + r];
        int chunk = sslot8 ^ (r & 7);
        async16(qkv + (row_base + gr) * 2304 + qcol + chunk * 8,
                &Qs[(is * 32 + wid * 8) * 64]);
    }
    __syncthreads();

    bf16x8 qf[2][2];
#pragma unroll
    for (int mi = 0; mi < 2; ++mi) {
        int r = wid * 32 + mi * 16 + l15;
#pragma unroll
        for (int ks = 0; ks < 2; ++ks)
            qf[mi][ks] = *(const bf16x8*)&Qs[r * 64 + (((ks * 4 + quad) ^ (r & 7)) * 8)];
    }
    // my qf reads must complete before staging overwrites the Qs region
    asm volatile("s_waitcnt lgkmcnt(0)" ::: "memory");
    __builtin_amdgcn_sched_barrier(0);
    __builtin_amdgcn_s_barrier();

    // ---- loop-invariant LDS element offsets ----
    const int off0 = l15 * 64 + (((0 * 4 + quad) ^ (l15 & 7)) * 8); // ks/ks2 = 0
    const int off1 = l15 * 64 + (((1 * 4 + quad) ^ (l15 & 7)) * 8); // ks/ks2 = 1
    const int pwb  = l15 * 88 + quad * 4;   // + mi*1408 + ki*16 (immediates)
    const int pfb  = l15 * 88 + quad * 8;   // + mi*1408 + ks2*32 (immediates)

    // ---- held global staging pointers (incremented per stage) ----
    const int rK = wid * 8 + srow8;                 // +32 for second chunk
    const int ck = sslot8 ^ (rK & 7);               // (is*32)&7 == 0
    const __bf16* kg0 = qkv + (row_base + rK) * 2304 + kcol + ck * 8;
    const __bf16* kg1 = kg0 + (size_t)32 * 2304;
    const __bf16* vg0 = vt + ((size_t)bh * 64 + rK) * 1024 + ck * 8;
    const __bf16* vg1 = vg0 + (size_t)32 * 1024;

    f32x4 acco[2][4];
#pragma unroll
    for (int mi = 0; mi < 2; ++mi)
#pragma unroll
        for (int ni = 0; ni < 4; ++ni) acco[mi][ni] = (f32x4)0.0f;
    float lsum[2] = {0.0f, 0.0f};

    const float cfac = 0.125f * 1.44269504088896340736f;

    // stage into buf kb: K @ kb*8192, V @ 16384 + kb*8192
#define ASTAGE(KB, VB) do {                                             \
        async16(kg0, smem + (KB) + wid * 1024);                         \
        async16(kg1, smem + (KB) + 4096 + wid * 1024);                  \
        async16(vg0, smem + (VB) + wid * 1024);                         \
        async16(vg1, smem + (VB) + 4096 + wid * 1024);                  \
        kg0 += (size_t)64 * 2304; kg1 += (size_t)64 * 2304;             \
        vg0 += 64; vg1 += 64;                                           \
    } while (0)

    auto compute = [&](const __bf16* Kb, const __bf16* Vb) {
#pragma unroll
        for (int half = 0; half < 2; ++half) {
            // ---- QK^T for ki = half*2 .. half*2+1 ----
            f32x4 accs[2][2];
#pragma unroll
            for (int ki = 0; ki < 2; ++ki)
#pragma unroll
                for (int mi = 0; mi < 2; ++mi) accs[ki][mi] = (f32x4)0.0f;
#pragma unroll
            for (int ks = 0; ks < 2; ++ks) {
                const int off = ks ? off1 : off0;
                bf16x8 kf0 = *(const bf16x8*)&Kb[(half * 2 + 0) * 1024 + off];
                bf16x8 kf1 = *(const bf16x8*)&Kb[(half * 2 + 1) * 1024 + off];
                accs[0][0] = mfma16(kf0, qf[0][ks], accs[0][0]);
                accs[0][1] = mfma16(kf0, qf[1][ks], accs[0][1]);
                accs[1][0] = mfma16(kf1, qf[0][ks], accs[1][0]);
                accs[1][1] = mfma16(kf1, qf[1][ks], accs[1][1]);
            }

            // ---- softmax (static bias -8; cancels in normalization) ----
#pragma unroll
            for (int ki = 0; ki < 2; ++ki)
#pragma unroll
                for (int mi = 0; mi < 2; ++mi) {
                    bf16x4 pk;
                    float s0 = __builtin_amdgcn_exp2f(accs[ki][mi][0] * cfac - 8.0f);
                    float s1 = __builtin_amdgcn_exp2f(accs[ki][mi][1] * cfac - 8.0f);
                    float s2 = __builtin_amdgcn_exp2f(accs[ki][mi][2] * cfac - 8.0f);
                    float s3 = __builtin_amdgcn_exp2f(accs[ki][mi][3] * cfac - 8.0f);
                    pk[0] = (__bf16)s0; pk[1] = (__bf16)s1;
                    pk[2] = (__bf16)s2; pk[3] = (__bf16)s3;
                    lsum[mi] += (s0 + s1) + (s2 + s3);
                    *(bf16x4*)&Pw[pwb + mi * 1408 + (half * 2 + ki) * 16] = pk;
                }

            // ---- PV for ks2 = half (same-wave LDS RAW; lgkmcnt orders it) ----
            {
                bf16x8 pf0 = *(const bf16x8*)&Pw[pfb + 0 * 1408 + half * 32];
                bf16x8 pf1 = *(const bf16x8*)&Pw[pfb + 1 * 1408 + half * 32];
                const int offv = half ? off1 : off0;
#pragma unroll
                for (int ni = 0; ni < 4; ++ni) {
                    bf16x8 vf = *(const bf16x8*)&Vb[ni * 1024 + offv];
                    acco[0][ni] = mfma16(pf0, vf, acco[0][ni]);
                    acco[1][ni] = mfma16(pf1, vf, acco[1][ni]);
                }
            }
        }
    };

    // ---- prologue: stage kt=0 into buf0 ----
    ASTAGE(0, 16384);

    // ---- main loop: 16 kt, unrolled x2 for literal buffer offsets ----
#pragma unroll 1
    for (int kt2 = 0; kt2 < 8; ++kt2) {
        asm volatile("s_waitcnt vmcnt(0) lgkmcnt(0)" ::: "memory");
        __builtin_amdgcn_s_barrier();
        ASTAGE(8192, 16384 + 8192);
        compute((const __bf16*)smem, (const __bf16*)(smem + 16384));
        asm volatile("s_waitcnt vmcnt(0) lgkmcnt(0)" ::: "memory");
        __builtin_amdgcn_s_barrier();
        if (kt2 < 7) ASTAGE(0, 16384);
        compute((const __bf16*)(smem + 8192), (const __bf16*)(smem + 16384 + 8192));
    }
#undef ASTAGE

#pragma unroll
    for (int off = 16; off < 64; off <<= 1) {
        lsum[0] += __shfl_xor(lsum[0], off, 64);
        lsum[1] += __shfl_xor(lsum[1], off, 64);
    }

#pragma unroll
    for (int mi = 0; mi < 2; ++mi) {
#pragma unroll
        for (int rg = 0; rg < 4; ++rg) {
            float inv = 1.0f / __shfl(lsum[mi], quad * 4 + rg, 64);
            int orow = q0 + wid * 32 + mi * 16 + quad * 4 + rg;
#pragma unroll
            for (int ni = 0; ni < 4; ++ni) {
                int ocol = h * 64 + ni * 16 + l15;
                O[(row_base + orow) * (size_t)ldo + ocol] = (__bf16)(acco[mi][ni][rg] * inv);
            }
        }
    }
}

// ---------------------------------------------------------------------------
// Workspace layout (bytes), total ~130.5 MB (see round-3 comment).
// ---------------------------------------------------------------------------
extern "C" void kernel_launch(void* const* d_in, const int* in_sizes, int n_in,
                              void* d_out, int out_size, void* d_ws, size_t ws_size,
                              hipStream_t stream) {
    (void)in_sizes; (void)n_in; (void)out_size; (void)ws_size;
    const void* x_raw    = d_in[0];
    const void* Wqkv_raw = d_in[1];
    const void* Wout_raw = d_in[2];
    const void* bout_raw = d_in[3];
    const int*  perm     = (const int*)d_in[4];

    char* ws = (char*)d_ws;
    int*    flag = (int*)ws;
    __bf16* Xc   = (__bf16*)(ws + 256);
    __bf16* QKV  = (__bf16*)(ws + 25166080);
    __bf16* Vt   = (__bf16*)(ws + 100663552);
    __bf16* Wqt  = (__bf16*)(ws + 125829376);
    __bf16* Wot  = (__bf16*)(ws + 129368320);
    __bf16* Obuf = QKV + 1536; // O[n][768] in QKV's V columns, ld 2304

    prep<<<1600, 256, 0, stream>>>(x_raw, Xc, Wqkv_raw, Wqt, Wout_raw, Wot, flag);
    gemm_bt<0><<<dim3(64, 18), 256, 0, stream>>>(Xc, 768, Wqt, nullptr, QKV, 2304, 768, nullptr, Vt);
    attn<<<dim3(192, 8), 256, 0, stream>>>(QKV, Vt, perm, Obuf, 2304);
    gemm_bt<1><<<dim3(64, 6), 256, 0, stream>>>(Obuf, 2304, Wot, bout_raw, d_out, 768, 768, flag, nullptr);
}